// Round 1
// baseline (416.706 us; speedup 1.0000x reference)
//
#include <hip/hip_runtime.h>

// Problem constants (from reference)
#define D_IN    256
#define D_OUT   64
#define NNODES  50000
#define NEDGES  1250000

// ---------------------------------------------------------------------------
// Kernel 1: h[N,64] = x[N,256] @ W[64,256]^T   (fp32, vector ALU — no fp32 MFMA)
// Block = 256 threads, one block per 64 rows of x. K split into 4 chunks of 64.
// LDS layout transposed ([k][row]) so the inner loop reads contiguous float4s
// (ds_read_b128). Pad 68 keeps 16B alignment (68*4=272=16*17) and 2-way banks.
// ---------------------------------------------------------------------------
__global__ __launch_bounds__(256) void gemm_h(
    const float* __restrict__ x, const float* __restrict__ W,
    float* __restrict__ h, int N)
{
    __shared__ __align__(16) float sX[64][68];  // [k][row]
    __shared__ __align__(16) float sW[64][68];  // [k][outcol]

    const int t    = threadIdx.x;
    const int row0 = blockIdx.x * 64;
    const int r0   = (t >> 4) * 4;   // row tile base   (0..60, step 4)
    const int c0   = (t & 15) * 4;   // col tile base   (0..60, step 4)

    float acc[4][4] = {};

    for (int kc = 0; kc < 4; ++kc) {
        // cooperative load of 64x64 chunks of x and W, transposed into LDS
        #pragma unroll
        for (int i = 0; i < 16; ++i) {
            int f   = t + i * 256;      // 0..4095
            int row = f >> 6;           // 0..63
            int kk  = f & 63;           // 0..63
            int gr  = row0 + row;
            sX[kk][row] = (gr < N) ? x[gr * D_IN + kc * 64 + kk] : 0.0f;
            sW[kk][row] = W[row * D_IN + kc * 64 + kk];  // row == out-col here
        }
        __syncthreads();

        #pragma unroll 8
        for (int kk = 0; kk < 64; ++kk) {
            float4 a = *(const float4*)&sX[kk][r0];
            float4 b = *(const float4*)&sW[kk][c0];
            float av[4] = {a.x, a.y, a.z, a.w};
            float bv[4] = {b.x, b.y, b.z, b.w};
            #pragma unroll
            for (int i = 0; i < 4; ++i)
                #pragma unroll
                for (int j = 0; j < 4; ++j)
                    acc[i][j] += av[i] * bv[j];
        }
        __syncthreads();
    }

    #pragma unroll
    for (int i = 0; i < 4; ++i) {
        int gr = row0 + r0 + i;
        if (gr < N) {
            float4 v = make_float4(acc[i][0], acc[i][1], acc[i][2], acc[i][3]);
            *(float4*)&h[gr * D_OUT + c0] = v;
        }
    }
}

// ---------------------------------------------------------------------------
// Kernel 2: out[n][j] = bias[j]  (d_out is poisoned 0xAA before every launch)
// ---------------------------------------------------------------------------
__global__ __launch_bounds__(256) void init_bias(
    float* __restrict__ out, const float* __restrict__ bias, int total)
{
    int i = blockIdx.x * blockDim.x + threadIdx.x;
    if (i < total) out[i] = bias[i & (D_OUT - 1)];
}

// ---------------------------------------------------------------------------
// Kernel 3: one wave per edge. lane j: out[dst][j] += w * h[src][j]
// src/dst/w loads are wave-uniform (broadcast); h gather is a coalesced 256B
// row read; atomics are coalesced across the wave (distinct addresses).
// ---------------------------------------------------------------------------
__global__ __launch_bounds__(256) void scatter_edges(
    const int* __restrict__ src, const int* __restrict__ dst,
    const float* __restrict__ wt, const float* __restrict__ h,
    float* __restrict__ out)
{
    long long gid = (long long)blockIdx.x * blockDim.x + threadIdx.x;
    int e    = (int)(gid >> 6);
    int lane = threadIdx.x & 63;
    if (e < NEDGES) {
        int   s = src[e];
        int   d = dst[e];
        float w = wt[e];
        float v = w * h[(long long)s * D_OUT + lane];
        atomicAdd(&out[(long long)d * D_OUT + lane], v);
    }
}

// ---------------------------------------------------------------------------
// Launch
// ---------------------------------------------------------------------------
extern "C" void kernel_launch(void* const* d_in, const int* in_sizes, int n_in,
                              void* d_out, int out_size, void* d_ws, size_t ws_size,
                              hipStream_t stream)
{
    const float* W     = (const float*)d_in[0];   // [64, 256]
    const float* bias  = (const float*)d_in[1];   // [64]
    const int*   edges = (const int*)  d_in[2];   // [2, E] (int delivery)
    const float* wt    = (const float*)d_in[3];   // [E]
    const float* x     = (const float*)d_in[4];   // [N, 256]
    float*       out   = (float*)d_out;           // [N, 64]
    float*       h     = (float*)d_ws;            // [N, 64] scratch (12.8 MB)

    const int* src = edges;            // edges[0, :]
    const int* dst = edges + NEDGES;   // edges[1, :]

    // 1) h = x @ W^T
    gemm_h<<<(NNODES + 63) / 64, 256, 0, stream>>>(x, W, h, NNODES);

    // 2) out = bias (broadcast)
    int total = NNODES * D_OUT;
    init_bias<<<(total + 255) / 256, 256, 0, stream>>>(out, bias, total);

    // 3) edge scatter-add: 64 lanes (one wave) per edge
    long long threads = (long long)NEDGES * 64;   // 80M lanes
    int blocks = (int)((threads + 255) / 256);    // 312500
    scatter_edges<<<blocks, 256, 0, stream>>>(src, dst, wt, h, out);
}

// Round 2
// 337.987 us; speedup vs baseline: 1.2329x; 1.2329x over previous
//
#include <hip/hip_runtime.h>
#include <hip/hip_bf16.h>

// Problem constants (from reference)
#define D_IN    256
#define D_OUT   64
#define NNODES  50000
#define NEDGES  1250000
#define NB_SCAN 196            // ceil(NNODES / 256)

// ---------------------------------------------------------------------------
// Kernel 1: h[N,64] = x[N,256] @ W[64,256]^T  (fp32 math, bf16 output)
// Block = 256 threads, one block per 64 rows. LDS transposed [k][row] so the
// inner loop is ds_read_b128 pairs + 16 FMA per k. Pad 68 keeps 16B alignment.
// ---------------------------------------------------------------------------
__global__ __launch_bounds__(256) void gemm_h(
    const float* __restrict__ x, const float* __restrict__ W,
    __hip_bfloat16* __restrict__ h, int N)
{
    __shared__ __align__(16) float sX[64][68];  // [k][row]
    __shared__ __align__(16) float sW[64][68];  // [k][outcol]

    const int t    = threadIdx.x;
    const int row0 = blockIdx.x * 64;
    const int r0   = (t >> 4) * 4;   // row tile base
    const int c0   = (t & 15) * 4;   // col tile base

    float acc[4][4] = {};

    for (int kc = 0; kc < 4; ++kc) {
        #pragma unroll
        for (int i = 0; i < 16; ++i) {
            int f   = t + i * 256;
            int row = f >> 6;
            int kk  = f & 63;
            int gr  = row0 + row;
            sX[kk][row] = (gr < N) ? x[gr * D_IN + kc * 64 + kk] : 0.0f;
            sW[kk][row] = W[row * D_IN + kc * 64 + kk];
        }
        __syncthreads();

        #pragma unroll 8
        for (int kk = 0; kk < 64; ++kk) {
            float4 a = *(const float4*)&sX[kk][r0];
            float4 b = *(const float4*)&sW[kk][c0];
            float av[4] = {a.x, a.y, a.z, a.w};
            float bv[4] = {b.x, b.y, b.z, b.w};
            #pragma unroll
            for (int i = 0; i < 4; ++i)
                #pragma unroll
                for (int j = 0; j < 4; ++j)
                    acc[i][j] += av[i] * bv[j];
        }
        __syncthreads();
    }

    #pragma unroll
    for (int i = 0; i < 4; ++i) {
        int gr = row0 + r0 + i;
        if (gr < N) {
            __align__(8) __hip_bfloat16 tmp[4];
            #pragma unroll
            for (int j = 0; j < 4; ++j) tmp[j] = __float2bfloat16(acc[i][j]);
            *(ushort4*)&h[(long long)gr * D_OUT + c0] = *(ushort4*)tmp;
        }
    }
}

// ---------------------------------------------------------------------------
// CSR build: histogram -> 2-level exclusive scan -> fill (counting sort)
// ---------------------------------------------------------------------------
__global__ __launch_bounds__(256) void hist_dst(
    const int* __restrict__ dst, int* __restrict__ counts)
{
    int e = blockIdx.x * 256 + threadIdx.x;
    if (e < NEDGES) atomicAdd(&counts[dst[e]], 1);
}

__global__ __launch_bounds__(256) void scanA(
    const int* __restrict__ counts, int* __restrict__ starts, int* __restrict__ bsum)
{
    int t = threadIdx.x;
    int i = blockIdx.x * 256 + t;
    int v = (i < NNODES) ? counts[i] : 0;
    __shared__ int s[256];
    s[t] = v; __syncthreads();
    #pragma unroll
    for (int off = 1; off < 256; off <<= 1) {
        int u = (t >= off) ? s[t - off] : 0;
        __syncthreads();
        s[t] += u;
        __syncthreads();
    }
    if (i < NNODES) starts[i] = s[t] - v;      // block-local exclusive
    if (t == 255) bsum[blockIdx.x] = s[255];   // block total
}

__global__ __launch_bounds__(256) void scanB(
    const int* __restrict__ bsum, int* __restrict__ boff)
{
    int t = threadIdx.x;
    int v = (t < NB_SCAN) ? bsum[t] : 0;
    __shared__ int s[256];
    s[t] = v; __syncthreads();
    #pragma unroll
    for (int off = 1; off < 256; off <<= 1) {
        int u = (t >= off) ? s[t - off] : 0;
        __syncthreads();
        s[t] += u;
        __syncthreads();
    }
    if (t < NB_SCAN) boff[t] = s[t] - v;       // exclusive block offsets
}

__global__ __launch_bounds__(256) void scanC(
    int* __restrict__ starts, const int* __restrict__ boff, int* __restrict__ cursor)
{
    int i = blockIdx.x * 256 + threadIdx.x;
    if (i < NNODES) {
        int v = starts[i] + boff[blockIdx.x];
        starts[i] = v;
        cursor[i] = v;
    }
}

// Place (src, wt) records grouped by dst. Device-scope 8B atomic stores avoid
// any cross-XCD false-sharing hazard on the write-back L2s.
__global__ __launch_bounds__(256) void fill_edges(
    const int* __restrict__ src, const int* __restrict__ dst,
    const float* __restrict__ wt, int* __restrict__ cursor,
    unsigned long long* __restrict__ recs)
{
    int e = blockIdx.x * 256 + threadIdx.x;
    if (e < NEDGES) {
        int d   = dst[e];
        int pos = atomicAdd(&cursor[d], 1);
        unsigned long long rec = (unsigned long long)(unsigned)src[e]
                               | ((unsigned long long)__float_as_uint(wt[e]) << 32);
        __hip_atomic_store(&recs[pos], rec, __ATOMIC_RELAXED, __HIP_MEMORY_SCOPE_AGENT);
    }
}

// ---------------------------------------------------------------------------
// Aggregation: one wave per node, lane = output column. Atomic-free.
// acc seeded with bias; one coalesced 128B bf16 row-gather per edge.
// ---------------------------------------------------------------------------
__global__ __launch_bounds__(256) void agg_nodes(
    const int2* __restrict__ recs, const int* __restrict__ starts,
    const int* __restrict__ counts, const __hip_bfloat16* __restrict__ h,
    const float* __restrict__ bias, float* __restrict__ out)
{
    int node = (blockIdx.x * 256 + threadIdx.x) >> 6;
    int lane = threadIdx.x & 63;
    if (node >= NNODES) return;

    float acc = bias[lane];
    int s0  = starts[node];
    int cnt = counts[node];
    int i = s0, e = s0 + cnt;
    for (; i + 1 < e; i += 2) {
        int2 r0 = recs[i];
        int2 r1 = recs[i + 1];
        float v0 = __bfloat162float(h[(long long)r0.x * D_OUT + lane]);
        float v1 = __bfloat162float(h[(long long)r1.x * D_OUT + lane]);
        acc += __int_as_float(r0.y) * v0 + __int_as_float(r1.y) * v1;
    }
    if (i < e) {
        int2 r = recs[i];
        acc += __int_as_float(r.y) * __bfloat162float(h[(long long)r.x * D_OUT + lane]);
    }
    out[(long long)node * D_OUT + lane] = acc;
}

// ---------------------------------------------------------------------------
// Fallback path (ws too small): bias init + per-edge atomics (R0 behavior)
// ---------------------------------------------------------------------------
__global__ __launch_bounds__(256) void init_bias(
    float* __restrict__ out, const float* __restrict__ bias, int total)
{
    int i = blockIdx.x * blockDim.x + threadIdx.x;
    if (i < total) out[i] = bias[i & (D_OUT - 1)];
}

__global__ __launch_bounds__(256) void scatter_edges(
    const int* __restrict__ src, const int* __restrict__ dst,
    const float* __restrict__ wt, const __hip_bfloat16* __restrict__ h,
    float* __restrict__ out)
{
    long long gid = (long long)blockIdx.x * blockDim.x + threadIdx.x;
    int e    = (int)(gid >> 6);
    int lane = threadIdx.x & 63;
    if (e < NEDGES) {
        int   s = src[e];
        int   d = dst[e];
        float w = wt[e];
        float v = w * __bfloat162float(h[(long long)s * D_OUT + lane]);
        atomicAdd(&out[(long long)d * D_OUT + lane], v);
    }
}

// ---------------------------------------------------------------------------
// Launch
// ---------------------------------------------------------------------------
extern "C" void kernel_launch(void* const* d_in, const int* in_sizes, int n_in,
                              void* d_out, int out_size, void* d_ws, size_t ws_size,
                              hipStream_t stream)
{
    const float* W     = (const float*)d_in[0];   // [64, 256]
    const float* bias  = (const float*)d_in[1];   // [64]
    const int*   edges = (const int*)  d_in[2];   // [2, E]
    const float* wt    = (const float*)d_in[3];   // [E]
    const float* x     = (const float*)d_in[4];   // [N, 256]
    float*       out   = (float*)d_out;           // [N, 64]

    const int* src = edges;
    const int* dst = edges + NEDGES;

    // workspace carve-up (bytes)
    char* ws = (char*)d_ws;
    const size_t OFF_H      = 0;                         // 6,400,000  (bf16 h)
    const size_t OFF_RECS   = 6400000;                   // 10,000,000 (int2 recs)
    const size_t OFF_COUNTS = 16400000;                  // 200,000
    const size_t OFF_STARTS = 16600000;                  // 200,000
    const size_t OFF_CURSOR = 16800000;                  // 200,000
    const size_t OFF_BSUM   = 17000000;                  // 784
    const size_t OFF_BOFF   = 17000800;                  // 784
    const size_t REQUIRED   = 17001600;

    __hip_bfloat16* h = (__hip_bfloat16*)(ws + OFF_H);

    // 1) h = x @ W^T  (bf16 out)
    gemm_h<<<(NNODES + 63) / 64, 256, 0, stream>>>(x, W, h, NNODES);

    if (ws_size >= REQUIRED) {
        unsigned long long* recs   = (unsigned long long*)(ws + OFF_RECS);
        int*                counts = (int*)(ws + OFF_COUNTS);
        int*                starts = (int*)(ws + OFF_STARTS);
        int*                cursor = (int*)(ws + OFF_CURSOR);
        int*                bsum   = (int*)(ws + OFF_BSUM);
        int*                boff   = (int*)(ws + OFF_BOFF);

        hipMemsetAsync(counts, 0, NNODES * sizeof(int), stream);

        int eb = (NEDGES + 255) / 256;   // 4883
        hist_dst<<<eb, 256, 0, stream>>>(dst, counts);
        scanA<<<NB_SCAN, 256, 0, stream>>>(counts, starts, bsum);
        scanB<<<1, 256, 0, stream>>>(bsum, boff);
        scanC<<<NB_SCAN, 256, 0, stream>>>(starts, boff, cursor);
        fill_edges<<<eb, 256, 0, stream>>>(src, dst, wt, cursor, recs);

        int nb = (NNODES * 64 + 255) / 256;  // 12500 blocks, 4 nodes each
        agg_nodes<<<nb, 256, 0, stream>>>((const int2*)recs, starts, counts, h, bias, out);
    } else {
        // fallback: R0 atomic path
        int total = NNODES * D_OUT;
        init_bias<<<(total + 255) / 256, 256, 0, stream>>>(out, bias, total);
        long long threads = (long long)NEDGES * 64;
        int blocks = (int)((threads + 255) / 256);
        scatter_edges<<<blocks, 256, 0, stream>>>(src, dst, wt, h, out);
    }
}

// Round 3
// 297.899 us; speedup vs baseline: 1.3988x; 1.1346x over previous
//
#include <hip/hip_runtime.h>
#include <hip/hip_bf16.h>

// Problem constants (from reference)
#define D_IN    256
#define D_OUT   64
#define NNODES  50000
#define NEDGES  1250000
#define NB_SCAN 196            // ceil(NNODES / 256)

typedef float f32x4 __attribute__((ext_vector_type(4)));
typedef short s16x8 __attribute__((ext_vector_type(8)));   // 8 bf16 (4 VGPRs)

// fp32 -> bf16 bits, round-to-nearest-even (inputs are finite randoms)
static __device__ __forceinline__ unsigned short f2bf(float f) {
    union { float f; unsigned u; } v; v.f = f;
    unsigned r = v.u + 0x7FFFu + ((v.u >> 16) & 1u);
    return (unsigned short)(r >> 16);
}
static __device__ __forceinline__ float bf2f(unsigned short b) {
    union { unsigned u; float f; } v; v.u = ((unsigned)b) << 16;
    return v.f;
}

// ---------------------------------------------------------------------------
// Kernel 1: h[N,64] = x[N,256] @ W[64,256]^T  via bf16 MFMA (fp32 accum).
// Block = 256 = 4 waves; wave w owns rows [blk*64 + 16w, +16), all 64 cols.
// A-frag: lane(m=lane&15, q=lane>>4) holds x[row=m][k=q*8+j]; B-frag: lane
// holds W[n=lane&15][k=q*8+j] (B[k][n] = W[n][k] — exactly the W^T we need).
// No LDS: x streamed from HBM (full 128B lines per wave-instr pair), W is
// L2-resident (64 KB). C/D layout: col=lane&15, row=q*4+reg.
// ---------------------------------------------------------------------------
__global__ __launch_bounds__(256) void gemm_h_mfma(
    const float* __restrict__ x, const float* __restrict__ W,
    unsigned short* __restrict__ h, int N)
{
    const int t    = threadIdx.x;
    const int wave = t >> 6;
    const int lane = t & 63;
    const int m    = lane & 15;
    const int q    = lane >> 4;
    const int rowA = blockIdx.x * 64 + wave * 16 + m;
    const int rowc = (rowA < N) ? rowA : (N - 1);

    const float* xr = x + (long long)rowc * D_IN + q * 8;

    f32x4 acc[4] = {};

    #pragma unroll
    for (int kb = 0; kb < 8; ++kb) {
        float4 a0 = *(const float4*)(xr + kb * 32);
        float4 a1 = *(const float4*)(xr + kb * 32 + 4);
        s16x8 af;
        af[0] = (short)f2bf(a0.x); af[1] = (short)f2bf(a0.y);
        af[2] = (short)f2bf(a0.z); af[3] = (short)f2bf(a0.w);
        af[4] = (short)f2bf(a1.x); af[5] = (short)f2bf(a1.y);
        af[6] = (short)f2bf(a1.z); af[7] = (short)f2bf(a1.w);

        #pragma unroll
        for (int c = 0; c < 4; ++c) {
            const float* wr = W + (c * 16 + m) * D_IN + kb * 32 + q * 8;
            float4 b0 = *(const float4*)wr;
            float4 b1 = *(const float4*)(wr + 4);
            s16x8 bf;
            bf[0] = (short)f2bf(b0.x); bf[1] = (short)f2bf(b0.y);
            bf[2] = (short)f2bf(b0.z); bf[3] = (short)f2bf(b0.w);
            bf[4] = (short)f2bf(b1.x); bf[5] = (short)f2bf(b1.y);
            bf[6] = (short)f2bf(b1.z); bf[7] = (short)f2bf(b1.w);
            acc[c] = __builtin_amdgcn_mfma_f32_16x16x32_bf16(af, bf, acc[c], 0, 0, 0);
        }
    }

    // C/D: col = c*16 + m, row = blk*64 + wave*16 + q*4 + r
    #pragma unroll
    for (int c = 0; c < 4; ++c) {
        #pragma unroll
        for (int r = 0; r < 4; ++r) {
            int gr = blockIdx.x * 64 + wave * 16 + q * 4 + r;
            if (gr < N)
                h[(long long)gr * D_OUT + c * 16 + m] = f2bf(acc[c][r]);
        }
    }
}

// ---------------------------------------------------------------------------
// CSR build: histogram -> 2-level exclusive scan -> fill (counting sort)
// ---------------------------------------------------------------------------
__global__ __launch_bounds__(256) void hist_dst(
    const int* __restrict__ dst, int* __restrict__ counts)
{
    int e = blockIdx.x * 256 + threadIdx.x;
    if (e < NEDGES) atomicAdd(&counts[dst[e]], 1);
}

__global__ __launch_bounds__(256) void scanA(
    const int* __restrict__ counts, int* __restrict__ starts, int* __restrict__ bsum)
{
    int t = threadIdx.x;
    int i = blockIdx.x * 256 + t;
    int v = (i < NNODES) ? counts[i] : 0;
    __shared__ int s[256];
    s[t] = v; __syncthreads();
    #pragma unroll
    for (int off = 1; off < 256; off <<= 1) {
        int u = (t >= off) ? s[t - off] : 0;
        __syncthreads();
        s[t] += u;
        __syncthreads();
    }
    if (i < NNODES) starts[i] = s[t] - v;
    if (t == 255) bsum[blockIdx.x] = s[255];
}

__global__ __launch_bounds__(256) void scanB(
    const int* __restrict__ bsum, int* __restrict__ boff)
{
    int t = threadIdx.x;
    int v = (t < NB_SCAN) ? bsum[t] : 0;
    __shared__ int s[256];
    s[t] = v; __syncthreads();
    #pragma unroll
    for (int off = 1; off < 256; off <<= 1) {
        int u = (t >= off) ? s[t - off] : 0;
        __syncthreads();
        s[t] += u;
        __syncthreads();
    }
    if (t < NB_SCAN) boff[t] = s[t] - v;
}

__global__ __launch_bounds__(256) void scanC(
    int* __restrict__ starts, const int* __restrict__ boff, int* __restrict__ cursor)
{
    int i = blockIdx.x * 256 + threadIdx.x;
    if (i < NNODES) {
        int v = starts[i] + boff[blockIdx.x];
        starts[i] = v;
        cursor[i] = v;
    }
}

__global__ __launch_bounds__(256) void fill_edges(
    const int* __restrict__ src, const int* __restrict__ dst,
    const float* __restrict__ wt, int* __restrict__ cursor,
    unsigned long long* __restrict__ recs)
{
    int e = blockIdx.x * 256 + threadIdx.x;
    if (e < NEDGES) {
        int d   = dst[e];
        int pos = atomicAdd(&cursor[d], 1);
        unsigned long long rec = (unsigned long long)(unsigned)src[e]
                               | ((unsigned long long)__float_as_uint(wt[e]) << 32);
        __hip_atomic_store(&recs[pos], rec, __ATOMIC_RELAXED, __HIP_MEMORY_SCOPE_AGENT);
    }
}

// ---------------------------------------------------------------------------
// Aggregation: one wave per node, lane = output column. node forced into an
// SGPR (readfirstlane) so starts/counts/recs go through scalar loads; edge
// loop unrolled x4 -> 4 independent h-gathers in flight per wave.
// ---------------------------------------------------------------------------
__global__ __launch_bounds__(256) void agg_nodes(
    const int2* __restrict__ recs, const int* __restrict__ starts,
    const int* __restrict__ counts, const unsigned short* __restrict__ h,
    const float* __restrict__ bias, float* __restrict__ out)
{
    int wid  = (blockIdx.x * 256 + threadIdx.x) >> 6;
    int node = __builtin_amdgcn_readfirstlane(wid);
    if (node >= NNODES) return;
    int lane = threadIdx.x & 63;

    float acc = bias[lane];
    int s0  = starts[node];
    int cnt = counts[node];
    int i = s0, e = s0 + cnt;

    for (; i + 3 < e; i += 4) {
        int2 r0 = recs[i + 0];
        int2 r1 = recs[i + 1];
        int2 r2 = recs[i + 2];
        int2 r3 = recs[i + 3];
        float v0 = bf2f(h[(long long)r0.x * D_OUT + lane]);
        float v1 = bf2f(h[(long long)r1.x * D_OUT + lane]);
        float v2 = bf2f(h[(long long)r2.x * D_OUT + lane]);
        float v3 = bf2f(h[(long long)r3.x * D_OUT + lane]);
        acc += __int_as_float(r0.y) * v0;
        acc += __int_as_float(r1.y) * v1;
        acc += __int_as_float(r2.y) * v2;
        acc += __int_as_float(r3.y) * v3;
    }
    for (; i < e; ++i) {
        int2 r = recs[i];
        acc += __int_as_float(r.y) * bf2f(h[(long long)r.x * D_OUT + lane]);
    }
    out[(long long)node * D_OUT + lane] = acc;
}

// ---------------------------------------------------------------------------
// Fallback path (ws too small): bias init + per-edge atomics
// ---------------------------------------------------------------------------
__global__ __launch_bounds__(256) void init_bias(
    float* __restrict__ out, const float* __restrict__ bias, int total)
{
    int i = blockIdx.x * blockDim.x + threadIdx.x;
    if (i < total) out[i] = bias[i & (D_OUT - 1)];
}

__global__ __launch_bounds__(256) void scatter_edges(
    const int* __restrict__ src, const int* __restrict__ dst,
    const float* __restrict__ wt, const unsigned short* __restrict__ h,
    float* __restrict__ out)
{
    long long gid = (long long)blockIdx.x * blockDim.x + threadIdx.x;
    int e    = (int)(gid >> 6);
    int lane = threadIdx.x & 63;
    if (e < NEDGES) {
        int   s = src[e];
        int   d = dst[e];
        float w = wt[e];
        float v = w * bf2f(h[(long long)s * D_OUT + lane]);
        atomicAdd(&out[(long long)d * D_OUT + lane], v);
    }
}

// ---------------------------------------------------------------------------
// Launch
// ---------------------------------------------------------------------------
extern "C" void kernel_launch(void* const* d_in, const int* in_sizes, int n_in,
                              void* d_out, int out_size, void* d_ws, size_t ws_size,
                              hipStream_t stream)
{
    const float* W     = (const float*)d_in[0];   // [64, 256]
    const float* bias  = (const float*)d_in[1];   // [64]
    const int*   edges = (const int*)  d_in[2];   // [2, E]
    const float* wt    = (const float*)d_in[3];   // [E]
    const float* x     = (const float*)d_in[4];   // [N, 256]
    float*       out   = (float*)d_out;           // [N, 64]

    const int* src = edges;
    const int* dst = edges + NEDGES;

    // workspace carve-up (bytes)
    char* ws = (char*)d_ws;
    const size_t OFF_H      = 0;                         // 6,400,000  (bf16 h)
    const size_t OFF_RECS   = 6400000;                   // 10,000,000 (int2 recs)
    const size_t OFF_COUNTS = 16400000;                  // 200,000
    const size_t OFF_STARTS = 16600000;                  // 200,000
    const size_t OFF_CURSOR = 16800000;                  // 200,000
    const size_t OFF_BSUM   = 17000000;                  // 784
    const size_t OFF_BOFF   = 17000800;                  // 784
    const size_t REQUIRED   = 17001600;

    unsigned short* h = (unsigned short*)(ws + OFF_H);

    // 1) h = x @ W^T  (bf16 MFMA, bf16 out)
    gemm_h_mfma<<<(NNODES + 63) / 64, 256, 0, stream>>>(x, W, h, NNODES);

    if (ws_size >= REQUIRED) {
        unsigned long long* recs   = (unsigned long long*)(ws + OFF_RECS);
        int*                counts = (int*)(ws + OFF_COUNTS);
        int*                starts = (int*)(ws + OFF_STARTS);
        int*                cursor = (int*)(ws + OFF_CURSOR);
        int*                bsum   = (int*)(ws + OFF_BSUM);
        int*                boff   = (int*)(ws + OFF_BOFF);

        hipMemsetAsync(counts, 0, NNODES * sizeof(int), stream);

        int eb = (NEDGES + 255) / 256;   // 4883
        hist_dst<<<eb, 256, 0, stream>>>(dst, counts);
        scanA<<<NB_SCAN, 256, 0, stream>>>(counts, starts, bsum);
        scanB<<<1, 256, 0, stream>>>(bsum, boff);
        scanC<<<NB_SCAN, 256, 0, stream>>>(starts, boff, cursor);
        fill_edges<<<eb, 256, 0, stream>>>(src, dst, wt, cursor, recs);

        int nb = (NNODES * 64 + 255) / 256;  // 12500 blocks, 4 nodes/block
        agg_nodes<<<nb, 256, 0, stream>>>((const int2*)recs, starts, counts, h, bias, out);
    } else {
        int total = NNODES * D_OUT;
        init_bias<<<(total + 255) / 256, 256, 0, stream>>>(out, bias, total);
        long long threads = (long long)NEDGES * 64;
        int blocks = (int)((threads + 255) / 256);
        scatter_edges<<<blocks, 256, 0, stream>>>(src, dst, wt, h, out);
    }
}